// Round 12
// baseline (453.467 us; speedup 1.0000x reference)
//
#include <hip/hip_runtime.h>
#include <hip/hip_bf16.h>

#define N_PTS 100000
#define KOFF 343
#define KPAD 352       // 22 chunks of 16
#define KC 16
#define NCH 22
#define EPS 1e-5f
#define SIDX_STR 17    // odd -> conflict-free idx reads

typedef __hip_bfloat16 bf16;
typedef __attribute__((ext_vector_type(4))) float f32x4;
typedef __attribute__((ext_vector_type(16))) float f32x16;
typedef __attribute__((ext_vector_type(8))) short s16x8;

// ---------------- pack: w_conv [343][32][32] f32 -> bf16 B-frags, padded to 352 ----------------
// wpk2 layout: [k][s][lane][j] = w_conv[k][s*16 + (lane>>5)*8 + j][lane&31]; k>=343 -> 0
__global__ __launch_bounds__(256) void pack_kernel(const float* __restrict__ w_conv,
                                                   bf16* __restrict__ wpk2) {
  int t = blockIdx.x * 256 + threadIdx.x;
  if (t >= KPAD * 128) return;
  int l = t & 63;
  int s = (t >> 6) & 1;
  int k = t >> 7;
  int col = l & 31;
  int kq = l >> 5;
  s16x8 v = {0, 0, 0, 0, 0, 0, 0, 0};
  if (k < KOFF) {
    const float* wk = w_conv + k * 1024;
    for (int j = 0; j < 8; ++j) {
      bf16 h = __float2bfloat16(wk[(s * 16 + kq * 8 + j) * 32 + col]);
      short sv;
      __builtin_memcpy(&sv, &h, 2);
      v[j] = sv;
    }
  }
  *reinterpret_cast<s16x8*>(reinterpret_cast<char*>(wpk2) + (size_t)t * 16) = v;
}

// ---------------- unary1: h1b = bf16( LN(feats @ w1) )  [N,32]; zeroes row N ----------------
__global__ __launch_bounds__(256) void unary1_kernel(const float* __restrict__ feats,
    const float* __restrict__ w1, const float* __restrict__ g1,
    const float* __restrict__ b1, bf16* __restrict__ h1b) {
  __shared__ float sf[8][128];
  __shared__ float sw[128 * 32];
  int tid = threadIdx.x;
  int rbase = blockIdx.x * 8;
  if (blockIdx.x == 0 && tid < 16)
    reinterpret_cast<int*>(h1b)[N_PTS * 16 + tid] = 0;   // zero row for invalid nbrs
  for (int i = tid; i < 1024; i += 256)
    reinterpret_cast<f32x4*>(sw)[i] = reinterpret_cast<const f32x4*>(w1)[i];
  {
    int i = tid;
    int r = rbase + (i >> 5);
    f32x4 v = reinterpret_cast<const f32x4*>(feats)[(size_t)r * 32 + (i & 31)];
    reinterpret_cast<f32x4*>(&sf[0][0])[i] = v;
  }
  __syncthreads();
  int half = tid >> 5;
  int c = tid & 31;
  int r = rbase + half;
  const float* frow = sf[half];
  float acc = 0.f;
  #pragma unroll 8
  for (int kk = 0; kk < 128; ++kk)
    acc += frow[kk] * sw[kk * 32 + c];
  float s = acc, s2 = acc * acc;
  #pragma unroll
  for (int m = 16; m >= 1; m >>= 1) {
    s  += __shfl_xor(s,  m, 64);
    s2 += __shfl_xor(s2, m, 64);
  }
  float mean = s * (1.f / 32.f);
  float var  = s2 * (1.f / 32.f) - mean * mean;
  float y = (acc - mean) * rsqrtf(var + EPS) * g1[c] + b1[c];
  h1b[(size_t)r * 32 + c] = __float2bfloat16(y);
}

// ---------------- conv v8: 128 pts/block, k-lockstep waves, B via LDS ----------------
// 4 waves, wave w owns tile w (32 pts), full k-range each (no reduction). Per 16-offset
// chunk: idx staged (translated -1 -> N_PTS) + B-frags staged (32 KB) cooperatively;
// waves consume B via ds_read_b128 (no TA cost) -> lane-addresses per 128pt-offset
// drop 1152 -> 768. A-frag: row=lane&31, kq=lane>>5; D: col=lane&31,
// row=(reg&3)+8*(reg>>2)+4*kq   [verified m74/m101]
__global__ __launch_bounds__(256) void conv_ls_kernel(const bf16* __restrict__ h1b,
    const int* __restrict__ nbr, const bf16* __restrict__ wpk2,
    float* __restrict__ h2) {
  __shared__ int sidx[128 * SIDX_STR];    // 8,704 B
  __shared__ s16x8 sB[KC * 128];          // 32,768 B
  int tid = threadIdx.x;
  int wave = tid >> 6;
  int l = tid & 63;
  int col = l & 31;
  int kq = l >> 5;
  int pbase0 = blockIdx.x * 128;
  const int* myrow = sidx + (wave * 32 + col) * SIDX_STR;
  const s16x8* h1s = reinterpret_cast<const s16x8*>(h1b);
  const s16x8* wsrc = reinterpret_cast<const s16x8*>(wpk2);
  f32x16 acc;
  #pragma unroll
  for (int i = 0; i < 16; ++i) acc[i] = 0.f;

  for (int ch = 0; ch < NCH; ++ch) {
    int kbase = ch * KC;
    // stage idx: 128 pts x 16 offsets, coalesced 64B groups, translate -1 -> N_PTS
    #pragma unroll
    for (int i = 0; i < 8; ++i) {
      int e = i * 256 + tid;               // 0..2047
      int p = e >> 4;
      int kk = e & 15;
      int pg = pbase0 + p;
      int k = kbase + kk;
      int v = (pg < N_PTS && k < KOFF) ? nbr[(size_t)pg * KOFF + k] : -1;
      sidx[p * SIDX_STR + kk] = v < 0 ? N_PTS : v;
    }
    // stage B: 16 offsets x 2 KB, linear copy
    {
      const s16x8* src = wsrc + (size_t)kbase * 128;
      #pragma unroll
      for (int i = 0; i < 8; ++i)
        sB[i * 256 + tid] = src[i * 256 + tid];
    }
    __syncthreads();
    #pragma unroll
    for (int kb = 0; kb < KC; kb += 4) {
      int id[4];
      #pragma unroll
      for (int j = 0; j < 4; ++j) id[j] = myrow[kb + j];
      s16x8 A0[4], A1[4], B0[4], B1[4];
      #pragma unroll
      for (int j = 0; j < 4; ++j) {
        const s16x8* r = h1s + (size_t)id[j] * 4;
        A0[j] = r[kq];
        A1[j] = r[2 + kq];
        B0[j] = sB[(kb + j) * 128 + l];
        B1[j] = sB[(kb + j) * 128 + 64 + l];
      }
      #pragma unroll
      for (int j = 0; j < 4; ++j) {
        acc = __builtin_amdgcn_mfma_f32_32x32x16_bf16(A0[j], B0[j], acc, 0, 0, 0);
        acc = __builtin_amdgcn_mfma_f32_32x32x16_bf16(A1[j], B1[j], acc, 0, 0, 0);
      }
    }
    __syncthreads();
  }

  int pb = pbase0 + wave * 32;
  #pragma unroll
  for (int reg = 0; reg < 16; ++reg) {
    int rrow = (reg & 3) + 8 * (reg >> 2) + 4 * kq;
    int row = pb + rrow;
    if (row < N_PTS) h2[(size_t)row * 32 + col] = acc[reg];
  }
}

// ---------------- unary2 v2: out = gelu(LN(h2 @ w2)) + feats, 2 rows/wave ----------------
__global__ __launch_bounds__(256) void unary2_kernel(const float* __restrict__ h2,
    const float* __restrict__ w2, const float* __restrict__ g2,
    const float* __restrict__ b2, const float* __restrict__ feats,
    float* __restrict__ out) {
  int tid = threadIdx.x;
  int wave = tid >> 6;
  int l = tid & 63;
  int r0 = blockIdx.x * 8 + wave * 2;     // rows r0, r0+1
  const f32x4* h0 = reinterpret_cast<const f32x4*>(h2 + (size_t)r0 * 32);
  const f32x4* h1r = reinterpret_cast<const f32x4*>(h2 + (size_t)(r0 + 1) * 32);
  float a00 = 0.f, a01 = 0.f, a10 = 0.f, a11 = 0.f;
  #pragma unroll
  for (int q = 0; q < 8; ++q) {
    f32x4 v0 = h0[q];
    f32x4 v1 = h1r[q];
    #pragma unroll
    for (int j = 0; j < 4; ++j) {
      int kk = q * 4 + j;
      float wlo = w2[kk * 128 + l];
      float whi = w2[kk * 128 + 64 + l];
      a00 += v0[j] * wlo;  a01 += v0[j] * whi;
      a10 += v1[j] * wlo;  a11 += v1[j] * whi;
    }
  }
  float s0 = a00 + a01, q0 = a00 * a00 + a01 * a01;
  float s1 = a10 + a11, q1 = a10 * a10 + a11 * a11;
  #pragma unroll
  for (int m = 32; m >= 1; m >>= 1) {
    s0 += __shfl_xor(s0, m, 64);
    q0 += __shfl_xor(q0, m, 64);
    s1 += __shfl_xor(s1, m, 64);
    q1 += __shfl_xor(q1, m, 64);
  }
  float m0 = s0 * (1.f / 128.f);
  float v0 = q0 * (1.f / 128.f) - m0 * m0;
  float i0 = rsqrtf(v0 + EPS);
  float m1 = s1 * (1.f / 128.f);
  float v1 = q1 * (1.f / 128.f) - m1 * m1;
  float i1 = rsqrtf(v1 + EPS);
  float glo = g2[l], ghi = g2[64 + l];
  float blo = b2[l], bhi = b2[64 + l];
  float y00 = (a00 - m0) * i0 * glo + blo;
  float y01 = (a01 - m0) * i0 * ghi + bhi;
  float y10 = (a10 - m1) * i1 * glo + blo;
  float y11 = (a11 - m1) * i1 * ghi + bhi;
  float e00 = 0.5f * y00 * (1.f + erff(y00 * 0.70710678118f));
  float e01 = 0.5f * y01 * (1.f + erff(y01 * 0.70710678118f));
  float e10 = 0.5f * y10 * (1.f + erff(y10 * 0.70710678118f));
  float e11 = 0.5f * y11 * (1.f + erff(y11 * 0.70710678118f));
  out[(size_t)r0 * 128 + l]            = e00 + feats[(size_t)r0 * 128 + l];
  out[(size_t)r0 * 128 + 64 + l]       = e01 + feats[(size_t)r0 * 128 + 64 + l];
  out[(size_t)(r0 + 1) * 128 + l]      = e10 + feats[(size_t)(r0 + 1) * 128 + l];
  out[(size_t)(r0 + 1) * 128 + 64 + l] = e11 + feats[(size_t)(r0 + 1) * 128 + 64 + l];
}

extern "C" void kernel_launch(void* const* d_in, const int* in_sizes, int n_in,
                              void* d_out, int out_size, void* d_ws, size_t ws_size,
                              hipStream_t stream) {
  const float* feats  = (const float*)d_in[0];
  const int*   nbr    = (const int*)d_in[1];
  const float* w1     = (const float*)d_in[2];
  const float* ln1_g  = (const float*)d_in[3];
  const float* ln1_b  = (const float*)d_in[4];
  const float* w_conv = (const float*)d_in[5];
  const float* w2     = (const float*)d_in[6];
  const float* ln2_g  = (const float*)d_in[7];
  const float* ln2_b  = (const float*)d_in[8];
  float* out = (float*)d_out;
  char* ws = (char*)d_ws;
  bf16*  h1b  = (bf16*)ws;                   // (100000+1)*32*2 = 6,400,064 B (row N = zeros)
  bf16*  wpk2 = (bf16*)(ws + 6400064);       // 352*128*16      =   720,896 B
  float* h2   = (float*)(ws + 7120960);      // 100000*32*4     = 12,800,000 B

  hipLaunchKernelGGL(pack_kernel,    dim3((KPAD * 128 + 255) / 256), dim3(256), 0, stream, w_conv, wpk2);
  hipLaunchKernelGGL(unary1_kernel,  dim3(N_PTS / 8),                dim3(256), 0, stream, feats, w1, ln1_g, ln1_b, h1b);
  hipLaunchKernelGGL(conv_ls_kernel, dim3((N_PTS + 127) / 128),      dim3(256), 0, stream, h1b, nbr, wpk2, h2);
  hipLaunchKernelGGL(unary2_kernel,  dim3(N_PTS / 8),                dim3(256), 0, stream, h2, w2, ln2_g, ln2_b, feats, out);
}

// Round 13
// 408.749 us; speedup vs baseline: 1.1094x; 1.1094x over previous
//
#include <hip/hip_runtime.h>
#include <hip/hip_bf16.h>

#define N_PTS 100000
#define KOFF 343
#define EPS 1e-5f
#define SSTR 87        // odd stage stride -> conflict-free idx reads

typedef __hip_bfloat16 bf16;
typedef __attribute__((ext_vector_type(4))) float f32x4;
typedef __attribute__((ext_vector_type(16))) float f32x16;
typedef __attribute__((ext_vector_type(8))) short s16x8;

// ---------------- pack: w_conv [343][32][32] f32 -> bf16 B-fragments ----------------
// wpk layout: [k][s][lane][j], element = w_conv[k][s*16 + (lane>>5)*8 + j][lane&31]
__global__ __launch_bounds__(256) void pack_kernel(const float* __restrict__ w_conv,
                                                   bf16* __restrict__ wpk) {
  int t = blockIdx.x * 256 + threadIdx.x;
  if (t >= KOFF * 128) return;
  int l = t & 63;
  int s = (t >> 6) & 1;
  int k = t >> 7;
  int col = l & 31;
  int kq = l >> 5;
  const float* wk = w_conv + k * 1024;
  s16x8 v;
  for (int j = 0; j < 8; ++j) {
    bf16 h = __float2bfloat16(wk[(s * 16 + kq * 8 + j) * 32 + col]);
    short sv;
    __builtin_memcpy(&sv, &h, 2);
    v[j] = sv;
  }
  *reinterpret_cast<s16x8*>(reinterpret_cast<char*>(wpk) + (size_t)t * 16) = v;
}

// ---------------- unary1: h1b = bf16( LN(feats @ w1) )  [N,32]; zeroes row N ----------------
__global__ __launch_bounds__(256) void unary1_kernel(const float* __restrict__ feats,
    const float* __restrict__ w1, const float* __restrict__ g1,
    const float* __restrict__ b1, bf16* __restrict__ h1b) {
  __shared__ float sf[8][128];
  __shared__ float sw[128 * 32];
  int tid = threadIdx.x;
  int rbase = blockIdx.x * 8;
  if (blockIdx.x == 0 && tid < 16)
    reinterpret_cast<int*>(h1b)[N_PTS * 16 + tid] = 0;   // zero row for invalid nbrs
  for (int i = tid; i < 1024; i += 256)
    reinterpret_cast<f32x4*>(sw)[i] = reinterpret_cast<const f32x4*>(w1)[i];
  {
    int i = tid;
    int r = rbase + (i >> 5);
    f32x4 v = reinterpret_cast<const f32x4*>(feats)[(size_t)r * 32 + (i & 31)];
    reinterpret_cast<f32x4*>(&sf[0][0])[i] = v;
  }
  __syncthreads();
  int half = tid >> 5;
  int c = tid & 31;
  int r = rbase + half;
  const float* frow = sf[half];
  float acc = 0.f;
  #pragma unroll 8
  for (int kk = 0; kk < 128; ++kk)
    acc += frow[kk] * sw[kk * 32 + c];
  float s = acc, s2 = acc * acc;
  #pragma unroll
  for (int m = 16; m >= 1; m >>= 1) {
    s  += __shfl_xor(s,  m, 64);
    s2 += __shfl_xor(s2, m, 64);
  }
  float mean = s * (1.f / 32.f);
  float var  = s2 * (1.f / 32.f) - mean * mean;
  float y = (acc - mean) * rsqrtf(var + EPS) * g1[c] + b1[c];
  h1b[(size_t)r * 32 + c] = __float2bfloat16(y);
}

// ---------------- conv v9: 4 tiles/block, waves k-LOCKSTEP (B L1-reuse), R10 inner loop ----------------
// Block = 256 thr = 4 waves; wave w owns tile w (32 pts of a 128-pt block); ALL waves
// sweep the same k-range per round -> B-frag lines hit L1 for 3 of 4 waves (B L2 bytes /4).
// idx staged 4 rounds x (128 pts x ~86 offsets) = 44.5 KB LDS, -1 -> N_PTS (zero row);
// no k-split -> no reduction, direct h2 writes. chunk=4 deep A/B buffering, no VGPR cap.
// A-frag: row=lane&31, kq=lane>>5; D: col=lane&31, row=(reg&3)+8*(reg>>2)+4*kq
template<int KCNT, int KBASE>
__device__ __forceinline__ void stage_round(const int* __restrict__ nbr,
    int* __restrict__ sbuf, int tid, int pbase0) {
  for (int i = tid; i < 128 * KCNT; i += 256) {
    int row = i / KCNT;                    // const divisor -> magic mul
    int kk = i - row * KCNT;
    int p = pbase0 + row;
    int v = (p < N_PTS) ? nbr[(size_t)p * KOFF + KBASE + kk] : -1;
    sbuf[row * SSTR + kk] = v < 0 ? N_PTS : v;
  }
}

template<int KCNT, int KBASE>
__device__ __forceinline__ void process_round(const int* __restrict__ sbuf,
    const bf16* __restrict__ h1b, const s16x8* __restrict__ wb,
    f32x16& acc, int wave, int l, int col, int kq) {
  const int* myrow = sbuf + (wave * 32 + col) * SSTR;
  const s16x8* h1s = reinterpret_cast<const s16x8*>(h1b);
  int id[4];
  #pragma unroll
  for (int j = 0; j < 4; ++j) id[j] = (j < KCNT) ? myrow[j] : N_PTS;
  for (int kb = 0; kb < KCNT; kb += 4) {
    s16x8 A0[4], A1[4], B0[4], B1[4];
    #pragma unroll
    for (int j = 0; j < 4; ++j) {
      const s16x8* r = h1s + (size_t)id[j] * 4;
      A0[j] = r[kq];
      A1[j] = r[2 + kq];
      int kc = (kb + j < KCNT) ? kb + j : KCNT - 1;
      B0[j] = wb[(size_t)(KBASE + kc) * 128 + l];
      B1[j] = wb[(size_t)(KBASE + kc) * 128 + 64 + l];
    }
    // prefetch next chunk's idx from LDS (hidden under the 16 global loads)
    int idn[4];
    #pragma unroll
    for (int j = 0; j < 4; ++j) idn[j] = (kb + 4 + j < KCNT) ? myrow[kb + 4 + j] : N_PTS;
    #pragma unroll
    for (int j = 0; j < 4; ++j) {
      acc = __builtin_amdgcn_mfma_f32_32x32x16_bf16(A0[j], B0[j], acc, 0, 0, 0);
      acc = __builtin_amdgcn_mfma_f32_32x32x16_bf16(A1[j], B1[j], acc, 0, 0, 0);
    }
    #pragma unroll
    for (int j = 0; j < 4; ++j) id[j] = idn[j];
  }
}

__global__ __launch_bounds__(256) void conv_lk_kernel(const bf16* __restrict__ h1b,
    const int* __restrict__ nbr, const bf16* __restrict__ wpk,
    float* __restrict__ h2) {
  __shared__ int sbuf[128 * SSTR];        // 44,544 B
  int tid = threadIdx.x;
  int wave = tid >> 6;
  int l = tid & 63;
  int col = l & 31;
  int kq = l >> 5;
  int pbase0 = blockIdx.x * 128;
  const s16x8* wb = reinterpret_cast<const s16x8*>(wpk);
  f32x16 acc;
  #pragma unroll
  for (int i = 0; i < 16; ++i) acc[i] = 0.f;

  stage_round<86, 0>(nbr, sbuf, tid, pbase0);
  __syncthreads();
  process_round<86, 0>(sbuf, h1b, wb, acc, wave, l, col, kq);
  __syncthreads();
  stage_round<86, 86>(nbr, sbuf, tid, pbase0);
  __syncthreads();
  process_round<86, 86>(sbuf, h1b, wb, acc, wave, l, col, kq);
  __syncthreads();
  stage_round<86, 172>(nbr, sbuf, tid, pbase0);
  __syncthreads();
  process_round<86, 172>(sbuf, h1b, wb, acc, wave, l, col, kq);
  __syncthreads();
  stage_round<85, 258>(nbr, sbuf, tid, pbase0);
  __syncthreads();
  process_round<85, 258>(sbuf, h1b, wb, acc, wave, l, col, kq);

  int pb = pbase0 + wave * 32;
  #pragma unroll
  for (int reg = 0; reg < 16; ++reg) {
    int rrow = (reg & 3) + 8 * (reg >> 2) + 4 * kq;
    int row = pb + rrow;
    if (row < N_PTS) h2[(size_t)row * 32 + col] = acc[reg];
  }
}

// ---------------- unary2 v2: out = gelu(LN(h2 @ w2)) + feats, 2 rows/wave ----------------
__global__ __launch_bounds__(256) void unary2_kernel(const float* __restrict__ h2,
    const float* __restrict__ w2, const float* __restrict__ g2,
    const float* __restrict__ b2, const float* __restrict__ feats,
    float* __restrict__ out) {
  int tid = threadIdx.x;
  int wave = tid >> 6;
  int l = tid & 63;
  int r0 = blockIdx.x * 8 + wave * 2;     // rows r0, r0+1
  const f32x4* h0 = reinterpret_cast<const f32x4*>(h2 + (size_t)r0 * 32);
  const f32x4* h1r = reinterpret_cast<const f32x4*>(h2 + (size_t)(r0 + 1) * 32);
  float a00 = 0.f, a01 = 0.f, a10 = 0.f, a11 = 0.f;
  #pragma unroll
  for (int q = 0; q < 8; ++q) {
    f32x4 v0 = h0[q];
    f32x4 v1 = h1r[q];
    #pragma unroll
    for (int j = 0; j < 4; ++j) {
      int kk = q * 4 + j;
      float wlo = w2[kk * 128 + l];
      float whi = w2[kk * 128 + 64 + l];
      a00 += v0[j] * wlo;  a01 += v0[j] * whi;
      a10 += v1[j] * wlo;  a11 += v1[j] * whi;
    }
  }
  float s0 = a00 + a01, q0 = a00 * a00 + a01 * a01;
  float s1 = a10 + a11, q1 = a10 * a10 + a11 * a11;
  #pragma unroll
  for (int m = 32; m >= 1; m >>= 1) {
    s0 += __shfl_xor(s0, m, 64);
    q0 += __shfl_xor(q0, m, 64);
    s1 += __shfl_xor(s1, m, 64);
    q1 += __shfl_xor(q1, m, 64);
  }
  float m0 = s0 * (1.f / 128.f);
  float v0 = q0 * (1.f / 128.f) - m0 * m0;
  float i0 = rsqrtf(v0 + EPS);
  float m1 = s1 * (1.f / 128.f);
  float v1 = q1 * (1.f / 128.f) - m1 * m1;
  float i1 = rsqrtf(v1 + EPS);
  float glo = g2[l], ghi = g2[64 + l];
  float blo = b2[l], bhi = b2[64 + l];
  float y00 = (a00 - m0) * i0 * glo + blo;
  float y01 = (a01 - m0) * i0 * ghi + bhi;
  float y10 = (a10 - m1) * i1 * glo + blo;
  float y11 = (a11 - m1) * i1 * ghi + bhi;
  float e00 = 0.5f * y00 * (1.f + erff(y00 * 0.70710678118f));
  float e01 = 0.5f * y01 * (1.f + erff(y01 * 0.70710678118f));
  float e10 = 0.5f * y10 * (1.f + erff(y10 * 0.70710678118f));
  float e11 = 0.5f * y11 * (1.f + erff(y11 * 0.70710678118f));
  out[(size_t)r0 * 128 + l]            = e00 + feats[(size_t)r0 * 128 + l];
  out[(size_t)r0 * 128 + 64 + l]       = e01 + feats[(size_t)r0 * 128 + 64 + l];
  out[(size_t)(r0 + 1) * 128 + l]      = e10 + feats[(size_t)(r0 + 1) * 128 + l];
  out[(size_t)(r0 + 1) * 128 + 64 + l] = e11 + feats[(size_t)(r0 + 1) * 128 + 64 + l];
}

extern "C" void kernel_launch(void* const* d_in, const int* in_sizes, int n_in,
                              void* d_out, int out_size, void* d_ws, size_t ws_size,
                              hipStream_t stream) {
  const float* feats  = (const float*)d_in[0];
  const int*   nbr    = (const int*)d_in[1];
  const float* w1     = (const float*)d_in[2];
  const float* ln1_g  = (const float*)d_in[3];
  const float* ln1_b  = (const float*)d_in[4];
  const float* w_conv = (const float*)d_in[5];
  const float* w2     = (const float*)d_in[6];
  const float* ln2_g  = (const float*)d_in[7];
  const float* ln2_b  = (const float*)d_in[8];
  float* out = (float*)d_out;
  char* ws = (char*)d_ws;
  bf16*  h1b = (bf16*)ws;                    // (100000+1)*32*2 = 6,400,064 B (row N = zeros)
  bf16*  wpk = (bf16*)(ws + 6400064);        // 343*128*16      =   702,464 B
  float* h2  = (float*)(ws + 7102528);       // 100000*32*4     = 12,800,000 B

  hipLaunchKernelGGL(pack_kernel,    dim3((KOFF * 128 + 255) / 256), dim3(256), 0, stream, w_conv, wpk);
  hipLaunchKernelGGL(unary1_kernel,  dim3(N_PTS / 8),                dim3(256), 0, stream, feats, w1, ln1_g, ln1_b, h1b);
  hipLaunchKernelGGL(conv_lk_kernel, dim3((N_PTS + 127) / 128),      dim3(256), 0, stream, h1b, nbr, wpk, h2);
  hipLaunchKernelGGL(unary2_kernel,  dim3(N_PTS / 8),                dim3(256), 0, stream, h2, w2, ln2_g, ln2_b, feats, out);
}

// Round 14
// 307.078 us; speedup vs baseline: 1.4767x; 1.3311x over previous
//
#include <hip/hip_runtime.h>
#include <hip/hip_bf16.h>

#define N_PTS 100000
#define KOFF 343
#define EPS 1e-5f
#define NTILES 3125    // N_PTS / 32
#define SSTR 173       // odd stage stride -> conflict-free idx reads

typedef __hip_bfloat16 bf16;
typedef __attribute__((ext_vector_type(4))) float f32x4;
typedef __attribute__((ext_vector_type(16))) float f32x16;
typedef __attribute__((ext_vector_type(8))) short s16x8;

// ---------------- pack: w_conv [343][32][32] f32 -> bf16 B-fragments ----------------
// wpk layout: [k][s][lane][j], element = w_conv[k][s*16 + (lane>>5)*8 + j][lane&31]
__global__ __launch_bounds__(256) void pack_kernel(const float* __restrict__ w_conv,
                                                   bf16* __restrict__ wpk) {
  int t = blockIdx.x * 256 + threadIdx.x;
  if (t >= KOFF * 128) return;
  int l = t & 63;
  int s = (t >> 6) & 1;
  int k = t >> 7;
  int col = l & 31;
  int kq = l >> 5;
  const float* wk = w_conv + k * 1024;
  s16x8 v;
  for (int j = 0; j < 8; ++j) {
    bf16 h = __float2bfloat16(wk[(s * 16 + kq * 8 + j) * 32 + col]);
    short sv;
    __builtin_memcpy(&sv, &h, 2);
    v[j] = sv;
  }
  *reinterpret_cast<s16x8*>(reinterpret_cast<char*>(wpk) + (size_t)t * 16) = v;
}

// ---------------- unary1: h1b = bf16( LN(feats @ w1) )  [N,32] ----------------
__global__ __launch_bounds__(256) void unary1_kernel(const float* __restrict__ feats,
    const float* __restrict__ w1, const float* __restrict__ g1,
    const float* __restrict__ b1, bf16* __restrict__ h1b) {
  __shared__ float sf[8][128];
  __shared__ float sw[128 * 32];
  int tid = threadIdx.x;
  int rbase = blockIdx.x * 8;
  for (int i = tid; i < 1024; i += 256)
    reinterpret_cast<f32x4*>(sw)[i] = reinterpret_cast<const f32x4*>(w1)[i];
  {
    int i = tid;
    int r = rbase + (i >> 5);
    f32x4 v = reinterpret_cast<const f32x4*>(feats)[(size_t)r * 32 + (i & 31)];
    reinterpret_cast<f32x4*>(&sf[0][0])[i] = v;
  }
  __syncthreads();
  int half = tid >> 5;
  int c = tid & 31;
  int r = rbase + half;
  const float* frow = sf[half];
  float acc = 0.f;
  #pragma unroll 8
  for (int kk = 0; kk < 128; ++kk)
    acc += frow[kk] * sw[kk * 32 + c];
  float s = acc, s2 = acc * acc;
  #pragma unroll
  for (int m = 16; m >= 1; m >>= 1) {
    s  += __shfl_xor(s,  m, 64);
    s2 += __shfl_xor(s2, m, 64);
  }
  float mean = s * (1.f / 32.f);
  float var  = s2 * (1.f / 32.f) - mean * mean;
  float y = (acc - mean) * rsqrtf(var + EPS) * g1[c] + b1[c];
  h1b[(size_t)r * 32 + c] = __float2bfloat16(y);
}

// ---------------- conv v6: R3 inner loop verbatim, staging split into 2 rounds ----------------
// Block = 256 thr = 4 waves, one 32-point tile, k-split x4. LDS = 22.1 KB
// -> ~7 blocks/CU. Inner loop: chunk=4 A/B buffering, cndmask zero for invalid, no VGPR cap.
// A-frag: row=lane&31, kq=lane>>5; D: col=lane&31, row=(reg&3)+8*(reg>>2)+4*kq
template<int KCNT, int KBASE>
__device__ __forceinline__ void process_round(const int* __restrict__ snbr,
    const bf16* __restrict__ h1b, const s16x8* __restrict__ wb,
    f32x16& acc, int wave, int l, int col, int kq) {
  int k0 = (KCNT * wave) >> 2;
  int k1 = (KCNT * (wave + 1)) >> 2;
  const int* myrow = snbr + col * SSTR;
  const s16x8 zv = {0, 0, 0, 0, 0, 0, 0, 0};
  for (int kb = k0; kb < k1; kb += 4) {
    int id[4];
    s16x8 A0[4], A1[4], B0[4], B1[4];
    #pragma unroll
    for (int j = 0; j < 4; ++j) {
      int k = kb + j;
      id[j] = (k < k1) ? myrow[k] : -1;
    }
    #pragma unroll
    for (int j = 0; j < 4; ++j) {
      int k = kb + j;
      int kc = (k < k1) ? k : (k1 - 1);
      const s16x8* r = reinterpret_cast<const s16x8*>(h1b + (size_t)(id[j] < 0 ? 0 : id[j]) * 32);
      A0[j] = r[kq];
      A1[j] = r[2 + kq];
      B0[j] = wb[(size_t)(KBASE + kc) * 128 + l];
      B1[j] = wb[(size_t)(KBASE + kc) * 128 + 64 + l];
    }
    #pragma unroll
    for (int j = 0; j < 4; ++j) {
      s16x8 a0 = id[j] < 0 ? zv : A0[j];
      s16x8 a1 = id[j] < 0 ? zv : A1[j];
      acc = __builtin_amdgcn_mfma_f32_32x32x16_bf16(a0, B0[j], acc, 0, 0, 0);
      acc = __builtin_amdgcn_mfma_f32_32x32x16_bf16(a1, B1[j], acc, 0, 0, 0);
    }
  }
}

__global__ __launch_bounds__(256) void conv_r2_kernel(const bf16* __restrict__ h1b,
    const int* __restrict__ nbr, const bf16* __restrict__ wpk,
    float* __restrict__ h2) {
  __shared__ int sbuf[32 * SSTR];         // 22,144 B; reused as float red[4096] (16 KB)
  int tid = threadIdx.x;
  int wave = tid >> 6;
  int l = tid & 63;
  int col = l & 31;
  int kq = l >> 5;
  int pbase = blockIdx.x * 32;
  const int* g = nbr + (size_t)pbase * KOFF;
  const s16x8* wb = reinterpret_cast<const s16x8*>(wpk);
  f32x16 acc;
  #pragma unroll
  for (int i = 0; i < 16; ++i) acc[i] = 0.f;

  // round 1: offsets [0,172)
  for (int i = tid; i < 32 * 172; i += 256) {
    int row = i / 172;                    // const divisor -> magic mul
    int kk = i - row * 172;
    sbuf[row * SSTR + kk] = g[row * KOFF + kk];
  }
  __syncthreads();
  process_round<172, 0>(sbuf, h1b, wb, acc, wave, l, col, kq);
  __syncthreads();
  // round 2: offsets [172,343)
  for (int i = tid; i < 32 * 171; i += 256) {
    int row = i / 171;
    int kk = i - row * 171;
    sbuf[row * SSTR + kk] = g[row * KOFF + 172 + kk];
  }
  __syncthreads();
  process_round<171, 172>(sbuf, h1b, wb, acc, wave, l, col, kq);
  __syncthreads();

  float* red = reinterpret_cast<float*>(sbuf);
  #pragma unroll
  for (int reg = 0; reg < 16; ++reg) {
    int rrow = (reg & 3) + 8 * (reg >> 2) + 4 * kq;
    red[wave * 1024 + rrow * 32 + col] = acc[reg];
  }
  __syncthreads();
  const f32x4* rv = reinterpret_cast<const f32x4*>(red);
  f32x4 s = rv[tid] + rv[256 + tid] + rv[512 + tid] + rv[768 + tid];
  reinterpret_cast<f32x4*>(h2 + (size_t)pbase * 32)[tid] = s;
}

// ---------------- unary2 v2: out = gelu(LN(h2 @ w2)) + feats, 2 rows/wave ----------------
__global__ __launch_bounds__(256) void unary2_kernel(const float* __restrict__ h2,
    const float* __restrict__ w2, const float* __restrict__ g2,
    const float* __restrict__ b2, const float* __restrict__ feats,
    float* __restrict__ out) {
  int tid = threadIdx.x;
  int wave = tid >> 6;
  int l = tid & 63;
  int r0 = blockIdx.x * 8 + wave * 2;     // rows r0, r0+1
  const f32x4* h0 = reinterpret_cast<const f32x4*>(h2 + (size_t)r0 * 32);
  const f32x4* h1r = reinterpret_cast<const f32x4*>(h2 + (size_t)(r0 + 1) * 32);
  float a00 = 0.f, a01 = 0.f, a10 = 0.f, a11 = 0.f;
  #pragma unroll
  for (int q = 0; q < 8; ++q) {
    f32x4 v0 = h0[q];
    f32x4 v1 = h1r[q];
    #pragma unroll
    for (int j = 0; j < 4; ++j) {
      int kk = q * 4 + j;
      float wlo = w2[kk * 128 + l];
      float whi = w2[kk * 128 + 64 + l];
      a00 += v0[j] * wlo;  a01 += v0[j] * whi;
      a10 += v1[j] * wlo;  a11 += v1[j] * whi;
    }
  }
  float s0 = a00 + a01, q0 = a00 * a00 + a01 * a01;
  float s1 = a10 + a11, q1 = a10 * a10 + a11 * a11;
  #pragma unroll
  for (int m = 32; m >= 1; m >>= 1) {
    s0 += __shfl_xor(s0, m, 64);
    q0 += __shfl_xor(q0, m, 64);
    s1 += __shfl_xor(s1, m, 64);
    q1 += __shfl_xor(q1, m, 64);
  }
  float m0 = s0 * (1.f / 128.f);
  float v0 = q0 * (1.f / 128.f) - m0 * m0;
  float i0 = rsqrtf(v0 + EPS);
  float m1 = s1 * (1.f / 128.f);
  float v1 = q1 * (1.f / 128.f) - m1 * m1;
  float i1 = rsqrtf(v1 + EPS);
  float glo = g2[l], ghi = g2[64 + l];
  float blo = b2[l], bhi = b2[64 + l];
  float y00 = (a00 - m0) * i0 * glo + blo;
  float y01 = (a01 - m0) * i0 * ghi + bhi;
  float y10 = (a10 - m1) * i1 * glo + blo;
  float y11 = (a11 - m1) * i1 * ghi + bhi;
  float e00 = 0.5f * y00 * (1.f + erff(y00 * 0.70710678118f));
  float e01 = 0.5f * y01 * (1.f + erff(y01 * 0.70710678118f));
  float e10 = 0.5f * y10 * (1.f + erff(y10 * 0.70710678118f));
  float e11 = 0.5f * y11 * (1.f + erff(y11 * 0.70710678118f));
  out[(size_t)r0 * 128 + l]            = e00 + feats[(size_t)r0 * 128 + l];
  out[(size_t)r0 * 128 + 64 + l]       = e01 + feats[(size_t)r0 * 128 + 64 + l];
  out[(size_t)(r0 + 1) * 128 + l]      = e10 + feats[(size_t)(r0 + 1) * 128 + l];
  out[(size_t)(r0 + 1) * 128 + 64 + l] = e11 + feats[(size_t)(r0 + 1) * 128 + 64 + l];
}

extern "C" void kernel_launch(void* const* d_in, const int* in_sizes, int n_in,
                              void* d_out, int out_size, void* d_ws, size_t ws_size,
                              hipStream_t stream) {
  const float* feats  = (const float*)d_in[0];
  const int*   nbr    = (const int*)d_in[1];
  const float* w1     = (const float*)d_in[2];
  const float* ln1_g  = (const float*)d_in[3];
  const float* ln1_b  = (const float*)d_in[4];
  const float* w_conv = (const float*)d_in[5];
  const float* w2     = (const float*)d_in[6];
  const float* ln2_g  = (const float*)d_in[7];
  const float* ln2_b  = (const float*)d_in[8];
  float* out = (float*)d_out;
  char* ws = (char*)d_ws;
  bf16*  h1b = (bf16*)ws;                    // 100000*32*2  = 6,400,000 B
  bf16*  wpk = (bf16*)(ws + 6400000);        // 343*128*16   =   702,464 B
  float* h2  = (float*)(ws + 7102464);       // 100000*32*4  = 12,800,000 B

  hipLaunchKernelGGL(pack_kernel,    dim3((KOFF * 128 + 255) / 256), dim3(256), 0, stream, w_conv, wpk);
  hipLaunchKernelGGL(unary1_kernel,  dim3(N_PTS / 8),                dim3(256), 0, stream, feats, w1, ln1_g, ln1_b, h1b);
  hipLaunchKernelGGL(conv_r2_kernel, dim3(NTILES),                   dim3(256), 0, stream, h1b, nbr, wpk, h2);
  hipLaunchKernelGGL(unary2_kernel,  dim3(N_PTS / 8),                dim3(256), 0, stream, h2, w2, ln2_g, ln2_b, feats, out);
}